// Round 14
// baseline (2442.296 us; speedup 1.0000x reference)
//
#include <hip/hip_runtime.h>
#include <cstdint>
#include <cstddef>

typedef _Float16 half8  __attribute__((ext_vector_type(8)));
typedef float    floatx4 __attribute__((ext_vector_type(4)));
typedef unsigned long long ull;

#define B_  64
#define T_  512
#define D_  512
#define H_  512
#define NG  2048   // 4*H

static __device__ __forceinline__ float fast_sigmoid(float x) {
  return 1.0f / (1.0f + __expf(-x));
}
static __device__ __forceinline__ float fast_tanh(float x) {
  x = fminf(15.0f, fmaxf(-15.0f, x));
  float e = __expf(2.0f * x);
  return (e - 1.0f) / (e + 1.0f);
}

// LDS-only barrier: drains lgkmcnt but NOT vmcnt (global ops stay in flight).
#define LDS_BARRIER() do {                                   \
    asm volatile("s_waitcnt lgkmcnt(0)" ::: "memory");       \
    __builtin_amdgcn_s_barrier();                            \
  } while (0)

#define TAGMASK 0x0000FFFF0000FFFFull

static __device__ __forceinline__ void unpack16(const ull* w8,
                                                half8& hv0, half8& hv1) {
  #pragma unroll
  for (int q = 0; q < 4; ++q) {
    hv0[2*q]   = __builtin_bit_cast(_Float16, (unsigned short)((unsigned)w8[q]   >> 16));
    hv0[2*q+1] = __builtin_bit_cast(_Float16, (unsigned short)(w8[q]   >> 48));
    hv1[2*q]   = __builtin_bit_cast(_Float16, (unsigned short)((unsigned)w8[4+q] >> 16));
    hv1[2*q+1] = __builtin_bit_cast(_Float16, (unsigned short)(w8[4+q] >> 48));
  }
}

// ---------------------------------------------------------------------------
// Kernel 1: input projections (unchanged — measured ~0.17 ms)
// ---------------------------------------------------------------------------
__global__ __launch_bounds__(256) void proj_kernel(
    const float* __restrict__ x,
    const float* __restrict__ Wc, const float* __restrict__ Wi,
    const float* __restrict__ Wf, const float* __restrict__ Wo,
    const float* __restrict__ bc, const float* __restrict__ bi,
    const float* __restrict__ bf2, const float* __restrict__ bo,
    _Float16* __restrict__ XG)
{
  const int tiles_n = NG / 64;
  int tM = blockIdx.x / tiles_n;
  int tN = blockIdx.x % tiles_n;
  int r0 = tM * 64;
  int t0 = r0 >> 6;
  int n0 = tN * 64;
  int g  = n0 >> 9;
  const float* W    = (g==0) ? Wc : (g==1) ? Wi : (g==2) ? Wf : Wo;
  const float* bias = (g==0) ? bc : (g==1) ? bi : (g==2) ? bf2 : bo;
  int j0 = n0 & (H_-1);

  __shared__ _Float16 Al[64*40];
  __shared__ _Float16 Bl[64*40];

  int tid  = threadIdx.x;
  int wave = tid >> 6;
  int lane = tid & 63;

  floatx4 acc[4] = {};

  int arow = tid >> 2;
  int ak0  = (tid & 3) * 8;
  const float* xsrc = x + ((size_t)arow * T_ + t0) * D_;

  int bcol = tid & 63;
  int bk0  = (tid >> 6) * 8;

  for (int k0 = 0; k0 < D_; k0 += 32) {
    half8 av;
    #pragma unroll
    for (int i = 0; i < 8; ++i) av[i] = (_Float16)xsrc[k0 + ak0 + i];
    *(half8*)&Al[arow*40 + ak0] = av;

    half8 bv;
    #pragma unroll
    for (int i = 0; i < 8; ++i)
      bv[i] = (_Float16)W[(size_t)(k0 + bk0 + i) * H_ + j0 + bcol];
    *(half8*)&Bl[bcol*40 + bk0] = bv;

    __syncthreads();

    half8 afrag = *(half8*)&Al[(wave*16 + (lane & 15))*40 + (lane >> 4)*8];
    #pragma unroll
    for (int ct = 0; ct < 4; ++ct) {
      half8 bfrag = *(half8*)&Bl[(ct*16 + (lane & 15))*40 + (lane >> 4)*8];
      acc[ct] = __builtin_amdgcn_mfma_f32_16x16x32_f16(afrag, bfrag, acc[ct], 0, 0, 0);
    }
    __syncthreads();
  }

  #pragma unroll
  for (int ct = 0; ct < 4; ++ct) {
    int col = n0 + ct*16 + (lane & 15);
    float bvs = bias[col & (H_-1)];
    #pragma unroll
    for (int i = 0; i < 4; ++i) {
      int row = r0 + wave*16 + (lane >> 4)*4 + i;
      XG[(size_t)row * NG + col] = (_Float16)(acc[ct][i] + bvs);
    }
  }
}

// ---------------------------------------------------------------------------
// Kernel 2: persistent scan, v14 = v13 + {pipelined A/B poll, padded LDS,
//   early per-i publish}. Sync fabric byte-identical to R9/R13.
//   h_lds: [ks(16)][row(16)][40 pad] halfs — staging writes & A-frag reads
//   both 2-way-max bank aliasing (free, m136).
// ---------------------------------------------------------------------------
__global__ __launch_bounds__(256) void scan_kernel(
    const _Float16* __restrict__ XG,
    const float* __restrict__ Uc, const float* __restrict__ Ui,
    const float* __restrict__ Uf, const float* __restrict__ Uo,
    float* __restrict__ out, unsigned* __restrict__ dbuf)
{
  __shared__ _Float16 h_lds[16*640];   // [ks][row][40] halfs = 20 KB

  int tid = threadIdx.x;
  int grp = blockIdx.x & 7;
  int member = blockIdx.x >> 3;

  int lane = tid & 63;
  int w    = tid >> 6;            // wave = n-tile (4 cols x 4 gates)
  int c16  = lane & 15;           // n within tile = jjl*4 + g
  int sub  = lane >> 4;           // k-subchunk (input) / row-group (output)
  int g    = c16 & 3;
  int jjl  = c16 >> 2;
  int jcol = member*16 + w*4 + jjl;   // output column j
  int hi   = sub;                      // C row group: batches hi*4+i
  bool pub = (g == 0) && (hi < 2);

  // ---- one-time: U fragments -> VGPRs (B-frag: lane holds B[col][k8]) ----
  const float* Ug = (g==0) ? Uc : (g==1) ? Ui : (g==2) ? Uf : Uo;
  half8 uf[16];
  #pragma unroll
  for (int ks = 0; ks < 16; ++ks) {
    half8 v;
    #pragma unroll
    for (int q = 0; q < 8; ++q)
      v[q] = (_Float16)Ug[(size_t)(ks*32 + sub*8 + q) * H_ + jcol];
    uf[ks] = v;
  }

  // consumer staging: thread's 16 polled words = h[b=sb][k=sm*16..+16)
  int sm  = tid >> 3;             // source member
  int sb  = tid & 7;              // batch row
  _Float16* stg = &h_lds[(sm >> 1)*640 + sb*40 + (sm & 1)*16];

  const _Float16* abase = &h_lds[c16*40 + sub*8];   // + ks*640 per k-step

  floatx4 c4 = {0.f, 0.f, 0.f, 0.f};
  float xg[4] = {0.f, 0.f, 0.f, 0.f};
  #pragma unroll
  for (int i = 0; i < 4; ++i)
    if (hi < 2)
      xg[i] = (float)XG[(size_t)(grp*8 + hi*4 + i) * NG + g*512 + jcol];

  for (int t = 0; t < T_; ++t) {
    LDS_BARRIER();   // prev step's A-frag reads complete before overwrite

    // ---- poll h^t: PIPELINED A/B sweeps (sampling period ~ RT/2) ----
    {
      const ull* src8 = (const ull*)dbuf
          + ((size_t)(t & 1))*16384u + (size_t)grp*2048u + (size_t)tid*8u;
      ull want2 = (ull)(unsigned)(t & 0xFFFF) * 0x0000000100000001ull;
      ull wA[8], wB[8];
      half8 hv0, hv1;
      #pragma unroll
      for (int q = 0; q < 8; ++q)
        wA[q] = __hip_atomic_load(src8 + q, __ATOMIC_RELAXED,
                                  __HIP_MEMORY_SCOPE_AGENT);
      for (;;) {
        // issue sweep B while A is being checked
        #pragma unroll
        for (int q = 0; q < 8; ++q)
          wB[q] = __hip_atomic_load(src8 + q, __ATOMIC_RELAXED,
                                    __HIP_MEMORY_SCOPE_AGENT);
        ull diff = 0;
        #pragma unroll
        for (int q = 0; q < 8; ++q) diff |= (wA[q] ^ want2) & TAGMASK;
        if (!diff) { unpack16(wA, hv0, hv1); break; }
        // reissue A while B is being checked
        #pragma unroll
        for (int q = 0; q < 8; ++q)
          wA[q] = __hip_atomic_load(src8 + q, __ATOMIC_RELAXED,
                                    __HIP_MEMORY_SCOPE_AGENT);
        diff = 0;
        #pragma unroll
        for (int q = 0; q < 8; ++q) diff |= (wB[q] ^ want2) & TAGMASK;
        if (!diff) { unpack16(wB, hv0, hv1); break; }
        __builtin_amdgcn_s_sleep(1);
      }
      *(half8*)stg       = hv0;
      *(half8*)(stg + 8) = hv1;
    }
    LDS_BARRIER();   // staged h visible

    // ---- MFMA dot: acc[b][c16] = sum_k h[b][k] * U[k][col] ----
    floatx4 a0 = {0.f,0.f,0.f,0.f}, a1 = {0.f,0.f,0.f,0.f};
    #pragma unroll
    for (int ks = 0; ks < 16; ks += 2) {
      half8 af0 = *(const half8*)(abase + ks*640);
      a0 = __builtin_amdgcn_mfma_f32_16x16x32_f16(af0, uf[ks],   a0, 0, 0, 0);
      half8 af1 = *(const half8*)(abase + (ks+1)*640);
      a1 = __builtin_amdgcn_mfma_f32_16x16x32_f16(af1, uf[ks+1], a1, 0, 0, 0);
    }

    // ---- gates + EARLY publish (per-i, as soon as computed) ----
    float hval[4];
    #pragma unroll
    for (int i = 0; i < 4; ++i) {
      float pre = (a0[i] + a1[i]) + xg[i];
      float act = (g == 0) ? fast_tanh(pre) : fast_sigmoid(pre);
      float t1  = __shfl_xor(act, 1);    // g0 <- sig(i)
      float ia  = act * t1;              // g0: tanh(a)*sig(i)
      float fv  = __shfl_xor(act, 2);    // g0 <- sig(f)
      float ov  = __shfl_xor(t1, 2);     // g0 <- sig(o)
      float cn  = fmaf(fv, c4[i], ia);
      c4[i] = cn;
      float hv = ov * fast_tanh(cn);
      hval[i] = hv;
      if (pub && (t + 1 < T_)) {
        unsigned wv = ((unsigned)__builtin_bit_cast(unsigned short,
                            (_Float16)hv) << 16)
                    | ((unsigned)(t + 1) & 0xFFFFu);
        unsigned widx = ((unsigned)((t + 1) & 1))*32768u + (unsigned)grp*4096u
                      + (unsigned)member*128u
                      + (unsigned)((hi*4 + i)*16 + w*4 + jjl);
        __hip_atomic_store(&dbuf[widx], wv,
                           __ATOMIC_RELAXED, __HIP_MEMORY_SCOPE_AGENT);
      }
    }

    // ---- out stores (in poll shadow) ----
    if (pub) {
      #pragma unroll
      for (int i = 0; i < 4; ++i)
        out[((size_t)(grp*8 + hi*4 + i) * T_ + t) * H_ + jcol] = hval[i];
    }

    // ---- prefetch XG for t+1 (rides under next poll) ----
    if (t + 1 < T_) {
      #pragma unroll
      for (int i = 0; i < 4; ++i)
        if (hi < 2)
          xg[i] = (float)XG[((size_t)(t + 1)*B_ + grp*8 + hi*4 + i) * NG
                            + g*512 + jcol];
    }
  }
}

// ---------------------------------------------------------------------------
extern "C" void kernel_launch(void* const* d_in, const int* in_sizes, int n_in,
                              void* d_out, int out_size, void* d_ws, size_t ws_size,
                              hipStream_t stream)
{
  const float* x  = (const float*)d_in[0];
  const float* Wc = (const float*)d_in[1];
  const float* Wi = (const float*)d_in[2];
  const float* Wf = (const float*)d_in[3];
  const float* Wo = (const float*)d_in[4];
  const float* Uc = (const float*)d_in[5];
  const float* Ui = (const float*)d_in[6];
  const float* Uf = (const float*)d_in[7];
  const float* Uo = (const float*)d_in[8];
  const float* bc = (const float*)d_in[9];
  const float* bi = (const float*)d_in[10];
  const float* bf2= (const float*)d_in[11];
  const float* bo = (const float*)d_in[12];
  float* out = (float*)d_out;

  const size_t XG_BYTES = (size_t)T_ * B_ * NG * sizeof(_Float16);  // 128 MiB
  const size_t DB_BYTES = (size_t)2 * 8 * 4096 * sizeof(unsigned);  // 256 KiB

  if (ws_size < XG_BYTES + DB_BYTES) return;

  _Float16* XG   = (_Float16*)d_ws;
  unsigned* dbuf = (unsigned*)((char*)d_ws + XG_BYTES);

  // tag 0 == "h^0 = 0 ready"; re-zeroed every launch (kills replay aliasing)
  (void)hipMemsetAsync(dbuf, 0, DB_BYTES, stream);

  proj_kernel<<<dim3((T_*B_/64) * (NG/64)), dim3(256), 0, stream>>>(
      x, Wc, Wi, Wf, Wo, bc, bi, bf2, bo, XG);

  scan_kernel<<<dim3(256), dim3(256), 0, stream>>>(
      XG, Uc, Ui, Uf, Uo, out, dbuf);
}

// Round 15
// 2070.017 us; speedup vs baseline: 1.1798x; 1.1798x over previous
//
#include <hip/hip_runtime.h>
#include <cstdint>
#include <cstddef>

typedef _Float16 half8  __attribute__((ext_vector_type(8)));
typedef float    floatx4 __attribute__((ext_vector_type(4)));
typedef unsigned long long ull;

#define B_  64
#define T_  512
#define D_  512
#define H_  512
#define NG  2048   // 4*H

static __device__ __forceinline__ float fast_sigmoid(float x) {
  return 1.0f / (1.0f + __expf(-x));
}
static __device__ __forceinline__ float fast_tanh(float x) {
  x = fminf(15.0f, fmaxf(-15.0f, x));
  float e = __expf(2.0f * x);
  return (e - 1.0f) / (e + 1.0f);
}

// LDS-only barrier: drains lgkmcnt but NOT vmcnt (global ops stay in flight).
#define LDS_BARRIER() do {                                   \
    asm volatile("s_waitcnt lgkmcnt(0)" ::: "memory");       \
    __builtin_amdgcn_s_barrier();                            \
  } while (0)

#define TAGMASK 0x0000FFFF0000FFFFull

// ---------------------------------------------------------------------------
// Kernel 1: input projections (unchanged — measured ~0.17 ms)
// ---------------------------------------------------------------------------
__global__ __launch_bounds__(256) void proj_kernel(
    const float* __restrict__ x,
    const float* __restrict__ Wc, const float* __restrict__ Wi,
    const float* __restrict__ Wf, const float* __restrict__ Wo,
    const float* __restrict__ bc, const float* __restrict__ bi,
    const float* __restrict__ bf2, const float* __restrict__ bo,
    _Float16* __restrict__ XG)
{
  const int tiles_n = NG / 64;
  int tM = blockIdx.x / tiles_n;
  int tN = blockIdx.x % tiles_n;
  int r0 = tM * 64;
  int t0 = r0 >> 6;
  int n0 = tN * 64;
  int g  = n0 >> 9;
  const float* W    = (g==0) ? Wc : (g==1) ? Wi : (g==2) ? Wf : Wo;
  const float* bias = (g==0) ? bc : (g==1) ? bi : (g==2) ? bf2 : bo;
  int j0 = n0 & (H_-1);

  __shared__ _Float16 Al[64*40];
  __shared__ _Float16 Bl[64*40];

  int tid  = threadIdx.x;
  int wave = tid >> 6;
  int lane = tid & 63;

  floatx4 acc[4] = {};

  int arow = tid >> 2;
  int ak0  = (tid & 3) * 8;
  const float* xsrc = x + ((size_t)arow * T_ + t0) * D_;

  int bcol = tid & 63;
  int bk0  = (tid >> 6) * 8;

  for (int k0 = 0; k0 < D_; k0 += 32) {
    half8 av;
    #pragma unroll
    for (int i = 0; i < 8; ++i) av[i] = (_Float16)xsrc[k0 + ak0 + i];
    *(half8*)&Al[arow*40 + ak0] = av;

    half8 bv;
    #pragma unroll
    for (int i = 0; i < 8; ++i)
      bv[i] = (_Float16)W[(size_t)(k0 + bk0 + i) * H_ + j0 + bcol];
    *(half8*)&Bl[bcol*40 + bk0] = bv;

    __syncthreads();

    half8 afrag = *(half8*)&Al[(wave*16 + (lane & 15))*40 + (lane >> 4)*8];
    #pragma unroll
    for (int ct = 0; ct < 4; ++ct) {
      half8 bfrag = *(half8*)&Bl[(ct*16 + (lane & 15))*40 + (lane >> 4)*8];
      acc[ct] = __builtin_amdgcn_mfma_f32_16x16x32_f16(afrag, bfrag, acc[ct], 0, 0, 0);
    }
    __syncthreads();
  }

  #pragma unroll
  for (int ct = 0; ct < 4; ++ct) {
    int col = n0 + ct*16 + (lane & 15);
    float bvs = bias[col & (H_-1)];
    #pragma unroll
    for (int i = 0; i < 4; ++i) {
      int row = r0 + wave*16 + (lane >> 4)*4 + i;
      XG[(size_t)row * NG + col] = (_Float16)(acc[ct][i] + bvs);
    }
  }
}

// ---------------------------------------------------------------------------
// Kernel 2: persistent scan, v15 = R13 poll (proven) + padded LDS (40-half
//   rows, 2-way-max aliasing) + early per-i publish. Sync fabric identical
//   to R9/R13: tagged words, compiler-emitted agent atomics only.
// ---------------------------------------------------------------------------
__global__ __launch_bounds__(256) void scan_kernel(
    const _Float16* __restrict__ XG,
    const float* __restrict__ Uc, const float* __restrict__ Ui,
    const float* __restrict__ Uf, const float* __restrict__ Uo,
    float* __restrict__ out, unsigned* __restrict__ dbuf)
{
  __shared__ _Float16 h_lds[16*640];   // [ks(16)][row(16)][40 pad] = 20 KB

  int tid = threadIdx.x;
  int grp = blockIdx.x & 7;
  int member = blockIdx.x >> 3;

  int lane = tid & 63;
  int w    = tid >> 6;            // wave = n-tile (4 cols x 4 gates)
  int c16  = lane & 15;           // n within tile = jjl*4 + g
  int sub  = lane >> 4;           // k-subchunk (input) / row-group (output)
  int g    = c16 & 3;
  int jjl  = c16 >> 2;
  int jcol = member*16 + w*4 + jjl;   // output column j
  int hi   = sub;                      // C row group: batches hi*4+i
  bool pub = (g == 0) && (hi < 2);

  // ---- one-time: U fragments -> VGPRs (B-frag: lane holds B[col][k8]) ----
  const float* Ug = (g==0) ? Uc : (g==1) ? Ui : (g==2) ? Uf : Uo;
  half8 uf[16];
  #pragma unroll
  for (int ks = 0; ks < 16; ++ks) {
    half8 v;
    #pragma unroll
    for (int q = 0; q < 8; ++q)
      v[q] = (_Float16)Ug[(size_t)(ks*32 + sub*8 + q) * H_ + jcol];
    uf[ks] = v;
  }

  // consumer staging: thread's 16 polled words = h[b=sb][k=sm*16..+16)
  int sm  = tid >> 3;             // source member
  int sb  = tid & 7;              // batch row
  _Float16* stg = &h_lds[(sm >> 1)*640 + sb*40 + (sm & 1)*16];

  const _Float16* abase = &h_lds[c16*40 + sub*8];   // + ks*640 per k-step

  floatx4 c4 = {0.f, 0.f, 0.f, 0.f};
  float xg[4] = {0.f, 0.f, 0.f, 0.f};
  #pragma unroll
  for (int i = 0; i < 4; ++i)
    if (hi < 2)
      xg[i] = (float)XG[(size_t)(grp*8 + hi*4 + i) * NG + g*512 + jcol];

  for (int t = 0; t < T_; ++t) {
    LDS_BARRIER();   // prev step's A-frag reads complete before overwrite

    // ---- poll h^t (R13-proven: bulk read + masked retry + backoff) ----
    {
      const ull* src8 = (const ull*)dbuf
          + ((size_t)(t & 1))*16384u + (size_t)grp*2048u + (size_t)tid*8u;
      ull want2 = (ull)(unsigned)(t & 0xFFFF) * 0x0000000100000001ull;
      ull w8[8];
      unsigned pend = 0xFFu;
      for (;;) {
        #pragma unroll
        for (int q = 0; q < 8; ++q)
          if (pend & (1u << q))
            w8[q] = __hip_atomic_load(src8 + q, __ATOMIC_RELAXED,
                                      __HIP_MEMORY_SCOPE_AGENT);
        unsigned npend = 0;
        #pragma unroll
        for (int q = 0; q < 8; ++q)
          if ((pend & (1u << q)) && ((w8[q] ^ want2) & TAGMASK))
            npend |= 1u << q;
        if (!npend) break;
        pend = npend;
        __builtin_amdgcn_s_sleep(2);
      }
      half8 hv0, hv1;
      #pragma unroll
      for (int q = 0; q < 4; ++q) {
        hv0[2*q]   = __builtin_bit_cast(_Float16, (unsigned short)((unsigned)w8[q]   >> 16));
        hv0[2*q+1] = __builtin_bit_cast(_Float16, (unsigned short)(w8[q]   >> 48));
        hv1[2*q]   = __builtin_bit_cast(_Float16, (unsigned short)((unsigned)w8[4+q] >> 16));
        hv1[2*q+1] = __builtin_bit_cast(_Float16, (unsigned short)(w8[4+q] >> 48));
      }
      *(half8*)stg       = hv0;
      *(half8*)(stg + 8) = hv1;
    }
    LDS_BARRIER();   // staged h visible

    // ---- MFMA dot: acc[b][c16] = sum_k h[b][k] * U[k][col] ----
    floatx4 a0 = {0.f,0.f,0.f,0.f}, a1 = {0.f,0.f,0.f,0.f};
    #pragma unroll
    for (int ks = 0; ks < 16; ks += 2) {
      half8 af0 = *(const half8*)(abase + ks*640);
      a0 = __builtin_amdgcn_mfma_f32_16x16x32_f16(af0, uf[ks],   a0, 0, 0, 0);
      half8 af1 = *(const half8*)(abase + (ks+1)*640);
      a1 = __builtin_amdgcn_mfma_f32_16x16x32_f16(af1, uf[ks+1], a1, 0, 0, 0);
    }

    // ---- gates + EARLY publish (per-i, as soon as computed) ----
    float hval[4];
    #pragma unroll
    for (int i = 0; i < 4; ++i) {
      float pre = (a0[i] + a1[i]) + xg[i];
      float act = (g == 0) ? fast_tanh(pre) : fast_sigmoid(pre);
      float t1  = __shfl_xor(act, 1);    // g0 <- sig(i)
      float ia  = act * t1;              // g0: tanh(a)*sig(i)
      float fv  = __shfl_xor(act, 2);    // g0 <- sig(f)
      float ov  = __shfl_xor(t1, 2);     // g0 <- sig(o)
      float cn  = fmaf(fv, c4[i], ia);
      c4[i] = cn;
      float hv = ov * fast_tanh(cn);
      hval[i] = hv;
      if (pub && (t + 1 < T_)) {
        unsigned wv = ((unsigned)__builtin_bit_cast(unsigned short,
                            (_Float16)hv) << 16)
                    | ((unsigned)(t + 1) & 0xFFFFu);
        unsigned widx = ((unsigned)((t + 1) & 1))*32768u + (unsigned)grp*4096u
                      + (unsigned)member*128u
                      + (unsigned)((hi*4 + i)*16 + w*4 + jjl);
        __hip_atomic_store(&dbuf[widx], wv,
                           __ATOMIC_RELAXED, __HIP_MEMORY_SCOPE_AGENT);
      }
    }

    // ---- out stores (in poll shadow) ----
    if (pub) {
      #pragma unroll
      for (int i = 0; i < 4; ++i)
        out[((size_t)(grp*8 + hi*4 + i) * T_ + t) * H_ + jcol] = hval[i];
    }

    // ---- prefetch XG for t+1 (rides under next poll) ----
    if (t + 1 < T_) {
      #pragma unroll
      for (int i = 0; i < 4; ++i)
        if (hi < 2)
          xg[i] = (float)XG[((size_t)(t + 1)*B_ + grp*8 + hi*4 + i) * NG
                            + g*512 + jcol];
    }
  }
}

// ---------------------------------------------------------------------------
extern "C" void kernel_launch(void* const* d_in, const int* in_sizes, int n_in,
                              void* d_out, int out_size, void* d_ws, size_t ws_size,
                              hipStream_t stream)
{
  const float* x  = (const float*)d_in[0];
  const float* Wc = (const float*)d_in[1];
  const float* Wi = (const float*)d_in[2];
  const float* Wf = (const float*)d_in[3];
  const float* Wo = (const float*)d_in[4];
  const float* Uc = (const float*)d_in[5];
  const float* Ui = (const float*)d_in[6];
  const float* Uf = (const float*)d_in[7];
  const float* Uo = (const float*)d_in[8];
  const float* bc = (const float*)d_in[9];
  const float* bi = (const float*)d_in[10];
  const float* bf2= (const float*)d_in[11];
  const float* bo = (const float*)d_in[12];
  float* out = (float*)d_out;

  const size_t XG_BYTES = (size_t)T_ * B_ * NG * sizeof(_Float16);  // 128 MiB
  const size_t DB_BYTES = (size_t)2 * 8 * 4096 * sizeof(unsigned);  // 256 KiB

  if (ws_size < XG_BYTES + DB_BYTES) return;

  _Float16* XG   = (_Float16*)d_ws;
  unsigned* dbuf = (unsigned*)((char*)d_ws + XG_BYTES);

  // tag 0 == "h^0 = 0 ready"; re-zeroed every launch (kills replay aliasing)
  (void)hipMemsetAsync(dbuf, 0, DB_BYTES, stream);

  proj_kernel<<<dim3((T_*B_/64) * (NG/64)), dim3(256), 0, stream>>>(
      x, Wc, Wi, Wf, Wo, bc, bi, bf2, bo, XG);

  scan_kernel<<<dim3(256), dim3(256), 0, stream>>>(
      XG, Uc, Ui, Uf, Uo, out, dbuf);
}